// Round 11
// baseline (301.778 us; speedup 1.0000x reference)
//
#include <hip/hip_runtime.h>
#include <hip/hip_cooperative_groups.h>
#include <math.h>

namespace cg = cooperative_groups;

#define B_ 8
#define N_ 2048
#define C_ 512
#define K_ 8
#define EPS 1e-6f
#define GENO_RATIO 0.1f

typedef __bf16 bf16x8 __attribute__((ext_vector_type(8)));
typedef float f32x4 __attribute__((ext_vector_type(4)));
typedef unsigned int u32;

__device__ __forceinline__ ushort f2bf(float x) {
    unsigned int u = __float_as_uint(x);
    u += 0x7fffu + ((u >> 16) & 1u);   // RNE (inputs are finite)
    return (ushort)(u >> 16);
}

__device__ __forceinline__ bf16x8 as_bf(uint4 x) {
    union { uint4 u; bf16x8 b; } t; t.u = x; return t.b;
}

// async global->LDS, 16B per lane. lds ptr must be wave-uniform (base+lane*16).
__device__ __forceinline__ void a_issue16(const ushort* g, ushort* l) {
    __builtin_amdgcn_global_load_lds(
        (const __attribute__((address_space(1))) u32*)g,
        (__attribute__((address_space(3))) u32*)l, 16, 0, 0);
}

// ---------------------------------------------------------------------------
// ws layout (float element offsets):
// [64,2112)            cnt (int)   [B,K] padded stride 32 (1 line/counter)
// [2112,4160)          mass        [B,K] padded stride 32
// [4160,36928)         hsum        [B,K,C]
// [36928,168000)       lw          [B,K,2048]
// [168000,1216576)     w1t2 (bf16) [K][16 cb][512 n][32 cc]       4 MB
// [1216576,34771008)   gathA (bf16)[64 p][16 cb][2048 pos][32 cc] 134 MB
// cnt/mass/hsum zeroed by phase 0 of the fused kernel (no memset launch).
// ---------------------------------------------------------------------------

// ONE cooperative kernel: phase0 zero -> gsync -> phase1 gating+transpose ->
// gsync -> phase2 grouped GEMM1 (r10 pipeline, 4 units/block, k=bid&7 XCD
// affinity) -> gsync -> phase3 combine. Removes 3 launch boundaries.
__global__ __launch_bounds__(512, 2) void k_all(
        const float* __restrict__ tokens, const float* __restrict__ gate_w,
        const float* __restrict__ gate_b, const float* __restrict__ geno_vec,
        const float* __restrict__ geno_w, const float* __restrict__ geno_b,
        const float* __restrict__ w1, const float* __restrict__ b1,
        const float* __restrict__ w2, const float* __restrict__ b2,
        int* cnt, float* mass, float* lw, ushort* gathA, ushort* w1t2,
        float* hsum, float* zbase, float* out) {
    cg::grid_group grid = cg::this_grid();
    __shared__ __align__(16) char pool[33280];
    int tid = threadIdx.x;
    int bid = blockIdx.x;

    // ---------------- phase 0: zero cnt/mass/hsum (36864 floats) -----------
    {
        int g = bid * 512 + tid;
        if (g < 9216) ((float4*)zbase)[g] = (float4){0.f, 0.f, 0.f, 0.f};
    }
    grid.sync();

    // ---------------- phase 1: gating (64 tok/block) + w1 transpose --------
    {
        int*   e01a  = (int*)pool;            // [64]
        int*   tpa   = (int*)(pool + 256);    // [64]
        float* tw0a  = (float*)(pool + 512);  // [64]
        float* tw1a  = (float*)(pool + 768);  // [64]
        int*   lcnt  = (int*)(pool + 1024);   // [8]
        float* lmass = (float*)(pool + 1056); // [8]
        int*   bse   = (int*)(pool + 1088);   // [8]
        if (tid < 8) { lcnt[tid] = 0; lmass[tid] = 0.f; }

        int wave = tid >> 6, lane = tid & 63;
        int t0 = bid * 64 + wave * 8;   // wave owns 8 tokens
        int b = bid >> 5;               // 32 blocks per batch
        int c0 = lane * 8;

        float4 gwlo[8], gwhi[8];
        const float* gwp = gate_w + (size_t)c0 * K_;
        #pragma unroll
        for (int m = 0; m < 8; ++m) {
            gwlo[m] = *(const float4*)(gwp + m * 8);
            gwhi[m] = *(const float4*)(gwp + m * 8 + 4);
        }

        float gb[8];
        {
            const float* grow = geno_vec + (size_t)b * C_ + c0;
            float4 gy0 = *(const float4*)(grow);
            float4 gy1 = *(const float4*)(grow + 4);
            float gv[8] = {gy0.x, gy0.y, gy0.z, gy0.w, gy1.x, gy1.y, gy1.z, gy1.w};
            const float* qwp = geno_w + (size_t)c0 * K_;
            float gd[8] = {0.f, 0.f, 0.f, 0.f, 0.f, 0.f, 0.f, 0.f};
            #pragma unroll
            for (int m = 0; m < 8; ++m) {
                float4 qlo = *(const float4*)(qwp + m * 8);
                float4 qhi = *(const float4*)(qwp + m * 8 + 4);
                gd[0] = fmaf(gv[m], qlo.x, gd[0]);
                gd[1] = fmaf(gv[m], qlo.y, gd[1]);
                gd[2] = fmaf(gv[m], qlo.z, gd[2]);
                gd[3] = fmaf(gv[m], qlo.w, gd[3]);
                gd[4] = fmaf(gv[m], qhi.x, gd[4]);
                gd[5] = fmaf(gv[m], qhi.y, gd[5]);
                gd[6] = fmaf(gv[m], qhi.z, gd[6]);
                gd[7] = fmaf(gv[m], qhi.w, gd[7]);
            }
            #pragma unroll
            for (int off = 32; off > 0; off >>= 1) {
                #pragma unroll
                for (int j = 0; j < 8; ++j) gd[j] += __shfl_xor(gd[j], off, 64);
            }
            #pragma unroll
            for (int j = 0; j < 8; ++j)
                gb[j] = gate_b[j] + GENO_RATIO * (gd[j] + geno_b[j]);
        }
        __syncthreads();   // lcnt/lmass zeroed before LDS atomics

        // -- gating for 8 tokens/wave; packed rows held in registers --
        uint4 orow[8];
        const float* trow = tokens + (size_t)t0 * C_ + c0;
        #pragma unroll 2
        for (int tt = 0; tt < 8; ++tt) {
            float4 v0 = *(const float4*)(trow + (size_t)tt * C_);
            float4 v1 = *(const float4*)(trow + (size_t)tt * C_ + 4);
            float tv[8] = {v0.x, v0.y, v0.z, v0.w, v1.x, v1.y, v1.z, v1.w};
            float acc[8];
            #pragma unroll
            for (int j = 0; j < 8; ++j) acc[j] = 0.f;
            #pragma unroll
            for (int m = 0; m < 8; ++m) {
                acc[0] = fmaf(tv[m], gwlo[m].x, acc[0]);
                acc[1] = fmaf(tv[m], gwlo[m].y, acc[1]);
                acc[2] = fmaf(tv[m], gwlo[m].z, acc[2]);
                acc[3] = fmaf(tv[m], gwlo[m].w, acc[3]);
                acc[4] = fmaf(tv[m], gwhi[m].x, acc[4]);
                acc[5] = fmaf(tv[m], gwhi[m].y, acc[5]);
                acc[6] = fmaf(tv[m], gwhi[m].z, acc[6]);
                acc[7] = fmaf(tv[m], gwhi[m].w, acc[7]);
            }
            orow[tt].x = (unsigned)f2bf(tv[0]) | ((unsigned)f2bf(tv[1]) << 16);
            orow[tt].y = (unsigned)f2bf(tv[2]) | ((unsigned)f2bf(tv[3]) << 16);
            orow[tt].z = (unsigned)f2bf(tv[4]) | ((unsigned)f2bf(tv[5]) << 16);
            orow[tt].w = (unsigned)f2bf(tv[6]) | ((unsigned)f2bf(tv[7]) << 16);
            #pragma unroll
            for (int off = 32; off > 0; off >>= 1) {
                #pragma unroll
                for (int j = 0; j < 8; ++j) acc[j] += __shfl_xor(acc[j], off, 64);
            }
            if (lane == 0) {
                float lg[8];
                #pragma unroll
                for (int j = 0; j < 8; ++j) lg[j] = acc[j] + gb[j];
                int i0 = 0; float v0m = lg[0];
                #pragma unroll
                for (int j = 1; j < 8; ++j) if (lg[j] > v0m) { v0m = lg[j]; i0 = j; }
                int i1 = -1; float v1m = -1e30f;
                #pragma unroll
                for (int j = 0; j < 8; ++j) if (j != i0 && lg[j] > v1m) { v1m = lg[j]; i1 = j; }
                float e = expf(v1m - v0m);
                float w0 = 1.f / (1.f + e);
                float w1s = e / (1.f + e);
                w0 = fmaxf(w0, EPS); w1s = fmaxf(w1s, EPS);
                float s = w0 + w1s; w0 /= s; w1s /= s;
                int lp0 = atomicAdd(&lcnt[i0], 1);
                int lp1 = atomicAdd(&lcnt[i1], 1);
                atomicAdd(&lmass[i0], w0);
                atomicAdd(&lmass[i1], w1s);
                int idx = wave * 8 + tt;
                e01a[idx] = i0 | (i1 << 4);
                tpa[idx]  = lp0 | (lp1 << 16);
                tw0a[idx] = w0; tw1a[idx] = w1s;
            }
        }
        __syncthreads();
        if (tid < 8) {
            int c = lcnt[tid];
            if (c > 0) {
                bse[tid] = atomicAdd(cnt + ((b * 8 + tid) << 5), c);
                atomicAdd(mass + ((b * 8 + tid) << 5), lmass[tid]);
            }
        }
        __syncthreads();
        size_t lofs = ((size_t)(lane >> 2) * 2048) * 32 + (size_t)(lane & 3) * 8;
        #pragma unroll 2
        for (int tt = 0; tt < 8; ++tt) {
            int idx = wave * 8 + tt;
            int e01 = e01a[idx], lp = tpa[idx];
            int i0 = e01 & 15, i1 = e01 >> 4;
            int pos0 = bse[i0] + (lp & 0xffff);
            int pos1 = bse[i1] + (lp >> 16);
            int p0 = b * 8 + i0, p1 = b * 8 + i1;
            *(uint4*)(gathA + ((size_t)(p0 * 16) * 2048 + pos0) * 32 + lofs) = orow[tt];
            *(uint4*)(gathA + ((size_t)(p1 * 16) * 2048 + pos1) * 32 + lofs) = orow[tt];
            if (lane == 0) {
                int n = (t0 + tt) & 2047;
                (void)n;
                lw[p0 * N_ + pos0] = tw0a[idx];
                lw[p1 * N_ + pos1] = tw1a[idx];
            }
        }
        __syncthreads();   // protect pool before transpose tiles

        // -- w1 transpose: two 256-thread units per block (512 units) --
        {
            int half = tid >> 8, t2 = tid & 255;
            int id2 = bid * 2 + half;
            int k = id2 >> 6;
            int c0t = ((id2 >> 3) & 7) * 64;
            int n0 = (id2 & 7) * 64;
            float (*tile)[65] = (float(*)[65])(pool + half * 16640);
            int tr = t2 >> 4;          // 0..15
            int tc4 = (t2 & 15) * 4;   // 0..60
            const float* src = w1 + (size_t)k * C_ * C_;
            #pragma unroll
            for (int i = 0; i < 4; ++i) {
                int c = c0t + tr + i * 16;
                float4 v = *(const float4*)(src + (size_t)c * C_ + n0 + tc4);
                tile[tr + i * 16][tc4 + 0] = v.x; tile[tr + i * 16][tc4 + 1] = v.y;
                tile[tr + i * 16][tc4 + 2] = v.z; tile[tr + i * 16][tc4 + 3] = v.w;
            }
            __syncthreads();
            #pragma unroll
            for (int i = 0; i < 4; ++i) {
                int rr = tr + i * 16;
                int n = n0 + rr;
                int c = c0t + tc4;
                int cb = c >> 5, cc = c & 31;
                uint2 o;
                o.x = (unsigned)f2bf(tile[tc4 + 0][rr]) | ((unsigned)f2bf(tile[tc4 + 1][rr]) << 16);
                o.y = (unsigned)f2bf(tile[tc4 + 2][rr]) | ((unsigned)f2bf(tile[tc4 + 3][rr]) << 16);
                *(uint2*)(w1t2 + ((size_t)(k * 16 + cb) * 512 + n) * 32 + cc) = o;
            }
        }
    }
    grid.sync();

    // ---------------- phase 2: grouped GEMM1 (4 units/block) ---------------
    {
        ushort (*As)[4096] = (ushort(*)[4096])pool;      // 4 slots x 128 x 32
        float* wls_s = (float*)(pool + 32768);           // [128]
        int kk = bid & 7;
        int wv = tid >> 6, lane = tid & 63;
        int ln15 = lane & 15, q = lane >> 4;

        #pragma unroll 1
        for (int u = 0; u < 4; ++u) {
            int idx = (bid >> 3) * 4 + u;
            int b2 = idx & 7, m = idx >> 3;
            int p = b2 * 8 + kk;
            int count = cnt[p << 5];
            int m0 = m * 128;
            __syncthreads();       // As/wls reuse fence between units
            if (m0 >= count) continue;
            if (tid < 128) {
                int mi = m0 + tid;
                wls_s[tid] = (mi < count) ? lw[p * N_ + mi] : 0.f;
            }
            __syncthreads();

            const ushort* ag = gathA
                + ((size_t)(p * 16) * 2048 + m0 + wv * 16 + ln15) * 32 + q * 8;
            const ushort* bb = w1t2
                + ((size_t)(kk * 16) * 512 + wv * 64 + ln15) * 32 + q * 8;

            f32x4 acc[8][4];
            #pragma unroll
            for (int mt = 0; mt < 8; ++mt)
                #pragma unroll
                for (int j = 0; j < 4; ++j) acc[mt][j] = (f32x4){0.f, 0.f, 0.f, 0.f};
            uint4 bA[4], bB[4];

#define ISSUE_A(T, S)                                                       \
            a_issue16(ag + (size_t)(T) * 65536, &As[S][0] + wv * 512);
#define LOAD_B(T, BANK)                                                     \
            {   _Pragma("unroll")                                           \
                for (int j = 0; j < 4; ++j)                                 \
                    BANK[j] = *(const uint4*)(bb + (size_t)(T) * 16384 + j * 512); }
#define CONSUME(S, BANK)                                                    \
            {   _Pragma("unroll")                                           \
                for (int mt = 0; mt < 8; ++mt) {                            \
                    bf16x8 af = *(const bf16x8*)(&As[S][0] + mt * 512       \
                                                 + q * 128 + ln15 * 8);     \
                    _Pragma("unroll")                                       \
                    for (int j = 0; j < 4; ++j)                             \
                        acc[mt][j] = __builtin_amdgcn_mfma_f32_16x16x32_bf16( \
                            af, as_bf(BANK[j]), acc[mt][j], 0, 0, 0);       \
                } }
#define WAITV(N)                                                            \
            {   asm volatile("s_waitcnt vmcnt(" #N ")" ::: "memory");       \
                __builtin_amdgcn_sched_barrier(0); }
#define BAR  __builtin_amdgcn_s_barrier()

            // prologue: A0 B0 A1 B1 A2 (outstanding 11)
            ISSUE_A(0, 0); LOAD_B(0, bA); ISSUE_A(1, 1); LOAD_B(1, bB); ISSUE_A(2, 2);
            #pragma unroll 1
            for (int t = 0; t < 12; t += 2) {
                WAITV(6); BAR;
                CONSUME((t) & 3, bA);
                LOAD_B(t + 2, bA); ISSUE_A(t + 3, (t + 3) & 3);
                WAITV(6); BAR;
                CONSUME((t + 1) & 3, bB);
                LOAD_B(t + 3, bB); ISSUE_A(t + 4, (t + 4) & 3);
            }
            WAITV(6); BAR; CONSUME(0, bA); LOAD_B(14, bA); ISSUE_A(15, 3);
            WAITV(6); BAR; CONSUME(1, bB); LOAD_B(15, bB);
            WAITV(5); BAR; CONSUME(2, bA);
            WAITV(0); BAR; CONSUME(3, bB);

#undef ISSUE_A
#undef LOAD_B
#undef CONSUME
#undef WAITV
#undef BAR

            float wrow[8][4];
            #pragma unroll
            for (int mt = 0; mt < 8; ++mt)
                #pragma unroll
                for (int rr = 0; rr < 4; ++rr)
                    wrow[mt][rr] = wls_s[mt * 16 + q * 4 + rr];
            const float* b1k = b1 + kk * C_;
            float* hp = hsum + (size_t)p * C_;
            #pragma unroll
            for (int j = 0; j < 4; ++j) {
                int n = wv * 64 + j * 16 + ln15;
                float bias = b1k[n];
                float s = 0.f;
                #pragma unroll
                for (int mt = 0; mt < 8; ++mt)
                    #pragma unroll
                    for (int rr = 0; rr < 4; ++rr) {
                        float wr = wrow[mt][rr];
                        float h = fmaxf(acc[mt][j][rr] + bias, 0.f);
                        s += (wr != 0.f) ? wr * h : 0.f;
                    }
                s += __shfl_xor(s, 16, 64);
                s += __shfl_xor(s, 32, 64);
                if (q == 0) atomicAdd(&hp[n], s);
            }
        }
    }
    grid.sync();

    // ---------------- phase 3: combine + finalize (blocks 0..127) ----------
    if (bid < 128) {
        float (*hs)[512] = (float(*)[512])pool;                 // 8 KB
        float (*racc)[4][64] = (float(*)[4][64])(pool + 8192);  // 8 KB
        int unit = bid;
        int et = unit & 7, k = (unit >> 3) & 7, bg = unit >> 6;
        int e0 = et * 64;
        {
            int bb = tid >> 7, c4 = (tid & 127) << 2;
            *(float4*)&hs[bb][c4] =
                *(const float4*)(hsum + ((size_t)((bg * 4 + bb) * 8 + k) << 9) + c4);
        }
        __syncthreads();
        int g = tid >> 6, lane = tid & 63;
        const float* w2p = w2 + (size_t)k * (C_ * C_) + e0 + lane;
        float a[4] = {0.f, 0.f, 0.f, 0.f};
        #pragma unroll 4
        for (int c = g; c < 512; c += 8) {
            float wvv = w2p[(size_t)c << 9];
            #pragma unroll
            for (int bb = 0; bb < 4; ++bb) a[bb] = fmaf(hs[bb][c], wvv, a[bb]);
        }
        #pragma unroll
        for (int bb = 0; bb < 4; ++bb) racc[g][bb][lane] = a[bb];
        __syncthreads();
        if (tid < 256) {
            int bb = tid >> 6, le = tid & 63;
            float s = 0.f;
            #pragma unroll
            for (int gg = 0; gg < 8; ++gg) s += racc[gg][bb][le];
            int pb = (bg * 4 + bb) * 8 + k;
            float mm = mass[pb << 5];
            out[((size_t)pb << 9) + e0 + le] =
                (s + b2[k * C_ + e0 + le] * mm) / fmaxf(mm, EPS);
        }
        if (unit == 0 && tid == 0) {
            float u[8]; float ssum = 0.f;
            for (int kk2 = 0; kk2 < 8; ++kk2) {
                int ck = 0;
                for (int bb2 = 0; bb2 < 8; ++bb2) ck += cnt[(bb2 * 8 + kk2) << 5];
                u[kk2] = (float)ck / (float)(B_ * N_);
                ssum += u[kk2];
            }
            float mean = ssum / 8.f;
            float var = 0.f;
            for (int kk2 = 0; kk2 < 8; ++kk2) { float d = u[kk2] - mean; var += d * d; }
            var /= 8.f;
            float denom = mean + EPS;
            out[B_ * K_ * C_] = var / (denom * denom);
        }
    }
}

extern "C" void kernel_launch(void* const* d_in, const int* in_sizes, int n_in,
                              void* d_out, int out_size, void* d_ws, size_t ws_size,
                              hipStream_t stream) {
    (void)in_sizes; (void)n_in; (void)out_size; (void)ws_size;
    const float* tokens   = (const float*)d_in[0];
    const float* geno_vec = (const float*)d_in[1];
    const float* gate_w   = (const float*)d_in[2];
    const float* gate_b   = (const float*)d_in[3];
    const float* geno_w   = (const float*)d_in[4];
    const float* geno_b   = (const float*)d_in[5];
    const float* w1       = (const float*)d_in[6];
    const float* b1       = (const float*)d_in[7];
    const float* w2       = (const float*)d_in[8];
    const float* b2       = (const float*)d_in[9];
    float* out = (float*)d_out;
    float* ws  = (float*)d_ws;

    int*    cnt   = (int*)(ws + 64);             // padded [64][32]
    float*  mass  = ws + 2112;                   // padded [64][32]
    float*  hsum  = ws + 4160;                   // [64][512]
    float*  lw    = ws + 36928;                  // [64][2048]
    ushort* w1t2  = (ushort*)(ws + 168000);      // 4 MB bf16
    ushort* gathA = (ushort*)(ws + 1216576);     // 134 MB bf16 panels
    float*  zbase = ws + 64;                     // zero region base

    void* args[] = {
        (void*)&tokens, (void*)&gate_w, (void*)&gate_b, (void*)&geno_vec,
        (void*)&geno_w, (void*)&geno_b, (void*)&w1, (void*)&b1,
        (void*)&w2, (void*)&b2, (void*)&cnt, (void*)&mass, (void*)&lw,
        (void*)&gathA, (void*)&w1t2, (void*)&hsum, (void*)&zbase, (void*)&out};
    hipError_t err = hipLaunchCooperativeKernel((const void*)k_all, dim3(256),
                                                dim3(512), args, 0, stream);
    if (err != hipSuccess) {
        // Fallback (should not trigger per harness support): serialize the
        // phases as plain launches of the same kernel body is impossible, so
        // emulate with a grid-wide sequence using the zero phase + 3 passes.
        // Minimal safe fallback: clear error and run nothing-fancy path.
        (void)hipGetLastError();
        // Plain-launch emulation: phase structure depends on grid.sync, so
        // we conservatively run the cooperative kernel as a normal launch
        // only if cooperative launch is unsupported is NOT safe; instead,
        // fail loudly by writing nothing (bench will catch mismatch).
    }
}

// Round 12
// 165.501 us; speedup vs baseline: 1.8234x; 1.8234x over previous
//
#include <hip/hip_runtime.h>
#include <math.h>

#define B_ 8
#define N_ 2048
#define C_ 512
#define K_ 8
#define EPS 1e-6f
#define GENO_RATIO 0.1f

typedef __bf16 bf16x8 __attribute__((ext_vector_type(8)));
typedef float f32x4 __attribute__((ext_vector_type(4)));
typedef unsigned int u32;

__device__ __forceinline__ ushort f2bf(float x) {
    unsigned int u = __float_as_uint(x);
    u += 0x7fffu + ((u >> 16) & 1u);   // RNE (inputs are finite)
    return (ushort)(u >> 16);
}

__device__ __forceinline__ bf16x8 as_bf(uint4 x) {
    union { uint4 u; bf16x8 b; } t; t.u = x; return t.b;
}

// async global->LDS, 16B per lane. lds ptr must be wave-uniform (base+lane*16).
__device__ __forceinline__ void a_issue16(const ushort* g, ushort* l) {
    __builtin_amdgcn_global_load_lds(
        (const __attribute__((address_space(1))) u32*)g,
        (__attribute__((address_space(3))) u32*)l, 16, 0, 0);
}

// ---------------------------------------------------------------------------
// ws layout (float element offsets):
// [64,2112)            cnt (int)   [B,K] padded stride 32 (1 line/counter)
// [2112,4160)          mass        [B,K] padded stride 32
// [4160,36928)         hsum        [B,K,C]
// [36928,168000)       lw          [B,K,2048]
// [168000,1216576)     w1t2 (bf16) [K][16 cb][512 n][32 cc]       4 MB
// [1216576,34771008)   gathA (bf16)[64 p][16 cb][2048 pos][32 cc] 134 MB
// memset zeroes [64,36928) (cnt/mass/hsum) each iteration.
// ---------------------------------------------------------------------------

// Gating blocks [0,512): 32 tokens/block (wave owns 8) — fat blocks keep the
// global-atomic reservation queue short (64 contenders/counter) and amortize
// phase drains. Packed bf16 rows stashed in a 32 KB LDS rowbuf (overlaid on
// the w1-transpose tile) so phase 3 is LDS-read -> coalesced scatter.
// Blocks [512,1024): w1 transpose+convert.
__global__ __launch_bounds__(256) void k_prep(const float* __restrict__ tokens,
                                              const float* __restrict__ gate_w,
                                              const float* __restrict__ gate_b,
                                              const float* __restrict__ geno_vec,
                                              const float* __restrict__ geno_w,
                                              const float* __restrict__ geno_b,
                                              const float* __restrict__ w1,
                                              int* __restrict__ cnt,
                                              float* __restrict__ mass,
                                              float* __restrict__ lw,
                                              ushort* __restrict__ gathA,
                                              ushort* __restrict__ w1t2) {
    // 33 KB shared pool: gating rowbuf [32 tok][64 lanes] uint4 (32 KB)
    // OR w1-transpose tile [64][65] f32 (16.6 KB)
    __shared__ __align__(16) float smem[8192];
    int tid = threadIdx.x;
    if (blockIdx.x < 512) {
        __shared__ int   lcnt[8];
        __shared__ float lmass[8];
        __shared__ int   bse[8];
        __shared__ int   te[32];      // i0 | i1<<4 per token
        __shared__ int   tp[32];      // lpos0 | lpos1<<16
        __shared__ float tw0_s[32], tw1_s[32];
        uint4 (*rowbuf)[64] = (uint4(*)[64])smem;
        if (tid < 8) { lcnt[tid] = 0; lmass[tid] = 0.f; }

        int wave = tid >> 6, lane = tid & 63;
        int t0 = blockIdx.x * 32 + wave * 8;   // wave owns 8 tokens
        int b = blockIdx.x >> 6;               // 64 blocks per batch
        int c0 = lane * 8;

        float4 gwlo[8], gwhi[8];
        const float* gwp = gate_w + (size_t)c0 * K_;
        #pragma unroll
        for (int m = 0; m < 8; ++m) {
            gwlo[m] = *(const float4*)(gwp + m * 8);
            gwhi[m] = *(const float4*)(gwp + m * 8 + 4);
        }

        float gb[8];
        {
            const float* grow = geno_vec + (size_t)b * C_ + c0;
            float4 gy0 = *(const float4*)(grow);
            float4 gy1 = *(const float4*)(grow + 4);
            float gv[8] = {gy0.x, gy0.y, gy0.z, gy0.w, gy1.x, gy1.y, gy1.z, gy1.w};
            const float* qwp = geno_w + (size_t)c0 * K_;
            float gd[8] = {0.f, 0.f, 0.f, 0.f, 0.f, 0.f, 0.f, 0.f};
            #pragma unroll
            for (int m = 0; m < 8; ++m) {
                float4 qlo = *(const float4*)(qwp + m * 8);
                float4 qhi = *(const float4*)(qwp + m * 8 + 4);
                gd[0] = fmaf(gv[m], qlo.x, gd[0]);
                gd[1] = fmaf(gv[m], qlo.y, gd[1]);
                gd[2] = fmaf(gv[m], qlo.z, gd[2]);
                gd[3] = fmaf(gv[m], qlo.w, gd[3]);
                gd[4] = fmaf(gv[m], qhi.x, gd[4]);
                gd[5] = fmaf(gv[m], qhi.y, gd[5]);
                gd[6] = fmaf(gv[m], qhi.z, gd[6]);
                gd[7] = fmaf(gv[m], qhi.w, gd[7]);
            }
            #pragma unroll
            for (int off = 32; off > 0; off >>= 1) {
                #pragma unroll
                for (int j = 0; j < 8; ++j) gd[j] += __shfl_xor(gd[j], off, 64);
            }
            #pragma unroll
            for (int j = 0; j < 8; ++j)
                gb[j] = gate_b[j] + GENO_RATIO * (gd[j] + geno_b[j]);
        }
        __syncthreads();   // lcnt/lmass zeroed before any LDS atomics

        // ---- phase 1: gating for 8 tokens/wave; rows -> LDS rowbuf ----
        const float* trow = tokens + (size_t)t0 * C_ + c0;
        #pragma unroll 2
        for (int tt = 0; tt < 8; ++tt) {
            float4 v0 = *(const float4*)(trow + (size_t)tt * C_);
            float4 v1 = *(const float4*)(trow + (size_t)tt * C_ + 4);
            float tv[8] = {v0.x, v0.y, v0.z, v0.w, v1.x, v1.y, v1.z, v1.w};

            float acc[8];
            #pragma unroll
            for (int j = 0; j < 8; ++j) acc[j] = 0.f;
            #pragma unroll
            for (int m = 0; m < 8; ++m) {
                acc[0] = fmaf(tv[m], gwlo[m].x, acc[0]);
                acc[1] = fmaf(tv[m], gwlo[m].y, acc[1]);
                acc[2] = fmaf(tv[m], gwlo[m].z, acc[2]);
                acc[3] = fmaf(tv[m], gwlo[m].w, acc[3]);
                acc[4] = fmaf(tv[m], gwhi[m].x, acc[4]);
                acc[5] = fmaf(tv[m], gwhi[m].y, acc[5]);
                acc[6] = fmaf(tv[m], gwhi[m].z, acc[6]);
                acc[7] = fmaf(tv[m], gwhi[m].w, acc[7]);
            }
            int idx = wave * 8 + tt;
            {
                uint4 o;
                o.x = (unsigned)f2bf(tv[0]) | ((unsigned)f2bf(tv[1]) << 16);
                o.y = (unsigned)f2bf(tv[2]) | ((unsigned)f2bf(tv[3]) << 16);
                o.z = (unsigned)f2bf(tv[4]) | ((unsigned)f2bf(tv[5]) << 16);
                o.w = (unsigned)f2bf(tv[6]) | ((unsigned)f2bf(tv[7]) << 16);
                rowbuf[idx][lane] = o;
            }
            #pragma unroll
            for (int off = 32; off > 0; off >>= 1) {
                #pragma unroll
                for (int j = 0; j < 8; ++j) acc[j] += __shfl_xor(acc[j], off, 64);
            }
            if (lane == 0) {
                float lg[8];
                #pragma unroll
                for (int j = 0; j < 8; ++j) lg[j] = acc[j] + gb[j];
                int i0 = 0; float v0m = lg[0];
                #pragma unroll
                for (int j = 1; j < 8; ++j) if (lg[j] > v0m) { v0m = lg[j]; i0 = j; }
                int i1 = -1; float v1m = -1e30f;
                #pragma unroll
                for (int j = 0; j < 8; ++j) if (j != i0 && lg[j] > v1m) { v1m = lg[j]; i1 = j; }
                float e = expf(v1m - v0m);
                float w0 = 1.f / (1.f + e);
                float w1s = e / (1.f + e);
                w0 = fmaxf(w0, EPS); w1s = fmaxf(w1s, EPS);
                float s = w0 + w1s; w0 /= s; w1s /= s;
                int lp0 = atomicAdd(&lcnt[i0], 1);
                int lp1 = atomicAdd(&lcnt[i1], 1);
                atomicAdd(&lmass[i0], w0);
                atomicAdd(&lmass[i1], w1s);
                te[idx] = i0 | (i1 << 4);
                tp[idx] = lp0 | (lp1 << 16);
                tw0_s[idx] = w0; tw1_s[idx] = w1s;
            }
        }
        __syncthreads();

        // ---- phase 2: one global atomic per touched expert ----
        if (tid < 8) {
            int c = lcnt[tid];
            if (c > 0) {
                bse[tid] = atomicAdd(cnt + ((b * 8 + tid) << 5), c);
                atomicAdd(mass + ((b * 8 + tid) << 5), lmass[tid]);
            }
        }
        __syncthreads();

        // ---- phase 3: LDS-read rows, scatter at base+lpos ----
        size_t lofs = ((size_t)(lane >> 2) * 2048) * 32 + (size_t)(lane & 3) * 8;
        #pragma unroll 2
        for (int tt = 0; tt < 8; ++tt) {
            int idx = wave * 8 + tt;
            int e01 = te[idx], lp = tp[idx];
            int i0 = e01 & 15, i1 = e01 >> 4;
            int pos0 = bse[i0] + (lp & 0xffff);
            int pos1 = bse[i1] + (lp >> 16);
            int p0 = b * 8 + i0, p1 = b * 8 + i1;
            uint4 o = rowbuf[idx][lane];
            *(uint4*)(gathA + ((size_t)(p0 * 16) * 2048 + pos0) * 32 + lofs) = o;
            *(uint4*)(gathA + ((size_t)(p1 * 16) * 2048 + pos1) * 32 + lofs) = o;
            if (lane == 0) {
                lw[p0 * N_ + pos0] = tw0_s[idx];
                lw[p1 * N_ + pos1] = tw1_s[idx];
            }
        }
    } else {
        // w1 transpose+convert: w1t2[k][cb][n][cc] = bf16(w1[k][cb*32+cc][n])
        int id2 = blockIdx.x - 512;
        int k = id2 >> 6;
        int c0 = ((id2 >> 3) & 7) * 64;
        int n0 = (id2 & 7) * 64;
        float (*tile)[65] = (float(*)[65])smem;
        int tr = tid >> 4;
        int tc4 = (tid & 15) * 4;
        const float* src = w1 + (size_t)k * C_ * C_;
        #pragma unroll
        for (int i = 0; i < 4; ++i) {
            int c = c0 + tr + i * 16;
            float4 v = *(const float4*)(src + (size_t)c * C_ + n0 + tc4);
            tile[tr + i * 16][tc4 + 0] = v.x; tile[tr + i * 16][tc4 + 1] = v.y;
            tile[tr + i * 16][tc4 + 2] = v.z; tile[tr + i * 16][tc4 + 3] = v.w;
        }
        __syncthreads();
        #pragma unroll
        for (int i = 0; i < 4; ++i) {
            int rr = tr + i * 16;
            int n = n0 + rr;
            int c = c0 + tc4;
            int cb = c >> 5, cc = c & 31;
            uint2 o;
            o.x = (unsigned)f2bf(tile[tc4 + 0][rr]) | ((unsigned)f2bf(tile[tc4 + 1][rr]) << 16);
            o.y = (unsigned)f2bf(tile[tc4 + 2][rr]) | ((unsigned)f2bf(tile[tc4 + 3][rr]) << 16);
            *(uint2*)(w1t2 + ((size_t)(k * 16 + cb) * 512 + n) * 32 + cc) = o;
        }
    }
}

// grouped GEMM1, MFMA bf16 — M=128 tile, 8 waves x 64 ch. A panels
// pre-gathered bf16, streamed linearly via global_load_lds into a 4-slot
// ring (8 KB/slot, wave wv stages rows wv*16..+16 at offset wv*512).
// B 2-deep in regs (4 uint4/bank). Ledger: 5 ops/wave/stage (1A + 4B),
// steady vmcnt(6), tail 6/6/5/0. id&7=k=XCD affinity.
__global__ __launch_bounds__(512, 2) void k_ffn1(const ushort* __restrict__ gathA,
                                                 const ushort* __restrict__ w1t2,
                                                 const float* __restrict__ b1,
                                                 const int* __restrict__ cnt,
                                                 const float* __restrict__ lw,
                                                 float* __restrict__ hsum) {
    int id = blockIdx.x;
    int k = id & 7, b = (id >> 3) & 7, m = id >> 6;
    int p = b * 8 + k;
    int count = cnt[p << 5];
    int m0 = m * 128;
    if (m0 >= count) return;

    __shared__ __align__(16) ushort As[4][4096];   // 4 slots x 128 rows x 32 cc
    __shared__ float wls_s[128];
    int tid = threadIdx.x;
    if (tid < 128) {
        int mi = m0 + tid;
        wls_s[tid] = (mi < count) ? lw[p * N_ + mi] : 0.f;
    }
    __syncthreads();

    int wv = tid >> 6, lane = tid & 63;
    int ln15 = lane & 15, q = lane >> 4;

    const ushort* ag = gathA + ((size_t)(p * 16) * 2048 + m0 + wv * 16 + ln15) * 32
                             + q * 8;
    const ushort* bb = w1t2 + ((size_t)(k * 16) * 512 + wv * 64 + ln15) * 32 + q * 8;

    f32x4 acc[8][4];
    #pragma unroll
    for (int mt = 0; mt < 8; ++mt)
        #pragma unroll
        for (int j = 0; j < 4; ++j) acc[mt][j] = (f32x4){0.f, 0.f, 0.f, 0.f};

    uint4 bA[4], bB[4];

#define ISSUE_A(T, S)                                                       \
    a_issue16(ag + (size_t)(T) * 65536, &As[S][0] + wv * 512);
#define LOAD_B(T, BANK)                                                     \
    {   _Pragma("unroll")                                                   \
        for (int j = 0; j < 4; ++j)                                         \
            BANK[j] = *(const uint4*)(bb + (size_t)(T) * 16384 + j * 512); }
#define CONSUME(S, BANK)                                                    \
    {   _Pragma("unroll")                                                   \
        for (int mt = 0; mt < 8; ++mt) {                                    \
            bf16x8 af = *(const bf16x8*)(&As[S][0] + mt * 512 + q * 128     \
                                         + ln15 * 8);                       \
            _Pragma("unroll")                                               \
            for (int j = 0; j < 4; ++j)                                     \
                acc[mt][j] = __builtin_amdgcn_mfma_f32_16x16x32_bf16(       \
                    af, as_bf(BANK[j]), acc[mt][j], 0, 0, 0);               \
        } }
#define WAITV(N)                                                            \
    {   asm volatile("s_waitcnt vmcnt(" #N ")" ::: "memory");               \
        __builtin_amdgcn_sched_barrier(0); }
#define BAR  __builtin_amdgcn_s_barrier()

    // prologue queue: A0 B0 A1 B1 A2  (outstanding 11)
    ISSUE_A(0, 0); LOAD_B(0, bA); ISSUE_A(1, 1); LOAD_B(1, bB); ISSUE_A(2, 2);

    #pragma unroll 1
    for (int t = 0; t < 12; t += 2) {
        WAITV(6); BAR;
        CONSUME((t) & 3, bA);
        LOAD_B(t + 2, bA); ISSUE_A(t + 3, (t + 3) & 3);
        WAITV(6); BAR;
        CONSUME((t + 1) & 3, bB);
        LOAD_B(t + 3, bB); ISSUE_A(t + 4, (t + 4) & 3);
    }
    WAITV(6); BAR; CONSUME(0, bA); LOAD_B(14, bA); ISSUE_A(15, 3);
    WAITV(6); BAR; CONSUME(1, bB); LOAD_B(15, bB);
    WAITV(5); BAR; CONSUME(2, bA);
    WAITV(0); BAR; CONSUME(3, bB);

#undef ISSUE_A
#undef LOAD_B
#undef CONSUME
#undef WAITV
#undef BAR

    // epilogue: bias+relu+gate-weight (poison-guarded); q-lane reduce;
    // 1 atomic per (wave, channel)
    float wrow[8][4];
    #pragma unroll
    for (int mt = 0; mt < 8; ++mt)
        #pragma unroll
        for (int rr = 0; rr < 4; ++rr) wrow[mt][rr] = wls_s[mt * 16 + q * 4 + rr];
    const float* b1k = b1 + k * C_;
    float* hp = hsum + (size_t)p * C_;
    #pragma unroll
    for (int j = 0; j < 4; ++j) {
        int n = wv * 64 + j * 16 + ln15;
        float bias = b1k[n];
        float s = 0.f;
        #pragma unroll
        for (int mt = 0; mt < 8; ++mt)
            #pragma unroll
            for (int rr = 0; rr < 4; ++rr) {
                float wr = wrow[mt][rr];
                float h = fmaxf(acc[mt][j][rr] + bias, 0.f);
                s += (wr != 0.f) ? wr * h : 0.f;
            }
        s += __shfl_xor(s, 16, 64);
        s += __shfl_xor(s, 32, 64);
        if (q == 0) atomicAdd(&hp[n], s);
    }
}

// fused combine+finalize: out[b,k,e] = (hsum[b,k,:]@w2[k,:,e]+b2*mass)/max(mass,eps)
// grid (et=8, k=8, bg=2): each block does 4 b's; 8 waves split c 8-ways.
__global__ __launch_bounds__(512) void k_comb(const float* __restrict__ hsum,
                                              const float* __restrict__ w2,
                                              const float* __restrict__ b2,
                                              const float* __restrict__ mass,
                                              const int* __restrict__ cnt,
                                              float* __restrict__ out) {
    int et = blockIdx.x, k = blockIdx.y, bg = blockIdx.z;
    int e0 = et * 64;
    __shared__ float hs[4][512];
    __shared__ float racc[8][4][64];
    int tid = threadIdx.x;
    {
        int bb = tid >> 7, c4 = (tid & 127) << 2;
        *(float4*)&hs[bb][c4] =
            *(const float4*)(hsum + ((size_t)((bg * 4 + bb) * 8 + k) << 9) + c4);
    }
    __syncthreads();
    int g = tid >> 6, lane = tid & 63;
    const float* w2p = w2 + (size_t)k * (C_ * C_) + e0 + lane;
    float a[4] = {0.f, 0.f, 0.f, 0.f};
    #pragma unroll 4
    for (int c = g; c < 512; c += 8) {
        float wvv = w2p[(size_t)c << 9];
        #pragma unroll
        for (int bb = 0; bb < 4; ++bb) a[bb] = fmaf(hs[bb][c], wvv, a[bb]);
    }
    #pragma unroll
    for (int bb = 0; bb < 4; ++bb) racc[g][bb][lane] = a[bb];
    __syncthreads();
    if (tid < 256) {
        int bb = tid >> 6, le = tid & 63;
        float s = 0.f;
        #pragma unroll
        for (int gg = 0; gg < 8; ++gg) s += racc[gg][bb][le];
        int pb = (bg * 4 + bb) * 8 + k;
        float mm = mass[pb << 5];
        out[((size_t)pb << 9) + e0 + le] =
            (s + b2[k * C_ + e0 + le] * mm) / fmaxf(mm, EPS);
    }
    if (et == 0 && k == 0 && bg == 0 && tid == 0) {
        float u[8]; float ssum = 0.f;
        for (int kk = 0; kk < 8; ++kk) {
            int ck = 0;
            for (int bb2 = 0; bb2 < 8; ++bb2) ck += cnt[(bb2 * 8 + kk) << 5];
            u[kk] = (float)ck / (float)(B_ * N_);
            ssum += u[kk];
        }
        float mean = ssum / 8.f;
        float var = 0.f;
        for (int kk = 0; kk < 8; ++kk) { float d = u[kk] - mean; var += d * d; }
        var /= 8.f;
        float denom = mean + EPS;
        out[B_ * K_ * C_] = var / (denom * denom);
    }
}

extern "C" void kernel_launch(void* const* d_in, const int* in_sizes, int n_in,
                              void* d_out, int out_size, void* d_ws, size_t ws_size,
                              hipStream_t stream) {
    (void)in_sizes; (void)n_in; (void)out_size; (void)ws_size;
    const float* tokens   = (const float*)d_in[0];
    const float* geno_vec = (const float*)d_in[1];
    const float* gate_w   = (const float*)d_in[2];
    const float* gate_b   = (const float*)d_in[3];
    const float* geno_w   = (const float*)d_in[4];
    const float* geno_b   = (const float*)d_in[5];
    const float* w1       = (const float*)d_in[6];
    const float* b1       = (const float*)d_in[7];
    const float* w2       = (const float*)d_in[8];
    const float* b2       = (const float*)d_in[9];
    float* out = (float*)d_out;
    float* ws  = (float*)d_ws;

    int*    cnt   = (int*)(ws + 64);             // padded [64][32]
    float*  mass  = ws + 2112;                   // padded [64][32]
    float*  hsum  = ws + 4160;                   // [64][512]
    float*  lw    = ws + 36928;                  // [64][2048]
    ushort* w1t2  = (ushort*)(ws + 168000);      // 4 MB bf16
    ushort* gathA = (ushort*)(ws + 1216576);     // 134 MB bf16 panels

    hipMemsetAsync(ws + 64, 0, (size_t)(36928 - 64) * sizeof(float), stream);
    k_prep<<<dim3(512 + 512), dim3(256), 0, stream>>>(tokens, gate_w, gate_b,
                                                      geno_vec, geno_w, geno_b,
                                                      w1, cnt, mass, lw,
                                                      gathA, w1t2);
    // grid: 8k x 8b x 16m = 1024; id&7=k keeps expert weights XCD-local
    k_ffn1<<<dim3(1024), dim3(512), 0, stream>>>(gathA, w1t2, b1,
                                                 cnt, lw, hsum);
    k_comb<<<dim3(8, K_, 2), dim3(512), 0, stream>>>(hsum, w2, b2, mass, cnt, out);
}